// Round 4
// baseline (706.714 us; speedup 1.0000x reference)
//
#include <hip/hip_runtime.h>
#include <hip/hip_fp16.h>
#include <cfloat>

#define BB 4
#define NN 4096
#define KK 16
#define NPTS (BB * NN)      // 16384
#define NT48 (48 * NPTS)    // per-layer tay floats, layout [48][NPTS]

typedef __attribute__((ext_vector_type(8))) _Float16 f16x8;
typedef __attribute__((ext_vector_type(4))) float f32x4;
typedef unsigned int u32;
typedef unsigned long long u64;

__device__ __forceinline__ short f2h(float v) {
  __half h = __float2half_rn(v);
  return __half_as_short(h);
}
__device__ __forceinline__ u32 mulh2(u32 a, __half2 t) {
  __half2 x = __hmul2(*(__half2*)&a, t);
  return *(u32*)&x;
}

// ---------------- KNN pass 1: top-16 distance VALUES within 512-cand chunk ----------------
// Values-only insertion chain: 3 instr/level vs 5 for (d,idx) pairs.
__global__ __launch_bounds__(256) void knn_part_vals(const float* __restrict__ pc,
                                                     float* __restrict__ partd) {
  __shared__ float4 sc[256];
  const int b = blockIdx.y;
  const int cz = blockIdx.z;
  const int n = blockIdx.x * 256 + threadIdx.x;
  const float* pcb = pc + (size_t)b * NN * 6;
  const float xn = pcb[n * 6 + 0];
  const float yn = pcb[n * 6 + 1];
  const float zn = pcb[n * 6 + 2];
  const float sqn = fmaf(zn, zn, fmaf(yn, yn, xn * xn));
  float dist[KK];
#pragma unroll
  for (int i = 0; i < KK; ++i) dist[i] = FLT_MAX;
  for (int t4 = 0; t4 < 2; ++t4) {
    const int base = cz * 512 + t4 * 256;
    const int m0 = base + threadIdx.x;
    const float x = pcb[m0 * 6 + 0];
    const float y = pcb[m0 * 6 + 1];
    const float z = pcb[m0 * 6 + 2];
    __syncthreads();
    sc[threadIdx.x] = make_float4(x, y, z, fmaf(z, z, fmaf(y, y, x * x)));
    __syncthreads();
    for (int j = 0; j < 256; ++j) {
      const float4 q = sc[j];
      const float dot = fmaf(zn, q.z, fmaf(yn, q.y, xn * q.x));
      const float d2 = fmaf(-2.0f, dot, sqn + q.w);
      if (d2 < dist[KK - 1]) {
        bool c_hi = true;
#pragma unroll
        for (int i = KK - 1; i > 0; --i) {
          const bool c_lo = d2 < dist[i - 1];
          dist[i] = c_lo ? dist[i - 1] : (c_hi ? d2 : dist[i]);
          c_hi = c_lo;
        }
        if (c_hi) dist[0] = d2;
      }
    }
  }
  float* od = partd + (((size_t)b * NN + n) * 8 + cz) * KK;
#pragma unroll
  for (int i = 0; i < KK; ++i) od[i] = dist[i];
}

// ---------------- merge 8 sorted value-lists -> exact 16th-smallest T; zero cnt ----------------
__global__ __launch_bounds__(256) void knn_merge_vals(const float* __restrict__ partd,
                                                      float* __restrict__ T,
                                                      int* __restrict__ cnt) {
  const int g = blockIdx.x * 256 + threadIdx.x;
  const float* pd = partd + (size_t)g * 128;
  int h[8];
#pragma unroll
  for (int c = 0; c < 8; ++c) h[c] = 0;
  float bd = FLT_MAX;
  for (int o = 0; o < KK; ++o) {
    bd = FLT_MAX;
    int bc = 0;
#pragma unroll
    for (int c = 0; c < 8; ++c) {
      const float d = (h[c] < KK) ? pd[c * KK + h[c]] : FLT_MAX;
      const bool better = d < bd;
      bd = better ? d : bd;
      bc = better ? c : bc;
    }
#pragma unroll
    for (int c = 0; c < 8; ++c) h[c] += (bc == c) ? 1 : 0;
  }
  T[g] = bd;   // 16th-smallest distance value (with multiplicity)
  cnt[g] = 0;  // re-zeroed every call (ws is poisoned)
}

// ---------------- collect: rescan, append (d2, j) with d2 <= T[g] ----------------
// d2 arithmetic is IDENTICAL (same fmaf chain) to knn_part_vals -> same float values.
__global__ __launch_bounds__(256) void knn_collect(const float* __restrict__ pc,
                                                   const float* __restrict__ T,
                                                   int* __restrict__ cnt,
                                                   float* __restrict__ candd,
                                                   int* __restrict__ candi) {
  __shared__ float4 sc[256];
  const int b = blockIdx.y;
  const int cz = blockIdx.z;
  const int n = blockIdx.x * 256 + threadIdx.x;
  const int g = b * NN + n;
  const float* pcb = pc + (size_t)b * NN * 6;
  const float xn = pcb[n * 6 + 0];
  const float yn = pcb[n * 6 + 1];
  const float zn = pcb[n * 6 + 2];
  const float sqn = fmaf(zn, zn, fmaf(yn, yn, xn * xn));
  const float t = T[g];
  for (int t4 = 0; t4 < 2; ++t4) {
    const int base = cz * 512 + t4 * 256;
    const int m0 = base + threadIdx.x;
    const float x = pcb[m0 * 6 + 0];
    const float y = pcb[m0 * 6 + 1];
    const float z = pcb[m0 * 6 + 2];
    __syncthreads();
    sc[threadIdx.x] = make_float4(x, y, z, fmaf(z, z, fmaf(y, y, x * x)));
    __syncthreads();
    for (int j = 0; j < 256; ++j) {
      const float4 q = sc[j];
      const float dot = fmaf(zn, q.z, fmaf(yn, q.y, xn * q.x));
      const float d2 = fmaf(-2.0f, dot, sqn + q.w);
      if (d2 <= t) {
        const int pos = atomicAdd(&cnt[g], 1);
        if (pos < 64) {  // typical count is exactly 16; 64 = duplicate-value safety cap
          candd[(size_t)g * 64 + pos] = d2;
          candi[(size_t)g * 64 + pos] = base + j;
        }
      }
    }
  }
}

// ---------------- final: exact top-16 by (d, idx) lexicographic ----------------
__global__ __launch_bounds__(256) void knn_sort16(const float* __restrict__ candd,
                                                  const int* __restrict__ candi,
                                                  const int* __restrict__ cnt,
                                                  int* __restrict__ idx) {
  const int g = blockIdx.x * 256 + threadIdx.x;
  const int m = min(cnt[g], 64);
  const float* cd = candd + (size_t)g * 64;
  const int* ci = candi + (size_t)g * 64;
  u64 used = 0;
  int* out = idx + (size_t)g * KK;
  for (int o = 0; o < KK; ++o) {
    float bd = FLT_MAX;
    int bi = 0x7fffffff, bs = 0;
    for (int i = 0; i < m; ++i) {
      if ((used >> i) & 1ull) continue;
      const float d = cd[i];
      const int ii = ci[i];
      const bool better = (d < bd) || (d == bd && ii < bi);
      bd = better ? d : bd;
      bi = better ? ii : bi;
      bs = better ? i : bs;
    }
    used |= 1ull << bs;
    out[o] = bi;
  }
}

// ---------------- pc -> ft0 f16 [p][8] (6 channels + pad) ----------------
__global__ __launch_bounds__(256) void pc2ft_kernel(const float* __restrict__ pc,
                                                    short* __restrict__ ft0) {
  const int i = blockIdx.x * 256 + threadIdx.x;
  if (i >= NPTS) return;
  const float* s = pc + (size_t)i * 6;
  short* d = ft0 + (size_t)i * 8;
#pragma unroll
  for (int c = 0; c < 6; ++c) d[c] = f2h(s[c]);
  d[6] = 0; d[7] = 0;
}

// ---------------- weights fp32 (o,(c,t),k) -> f16 permuted [o][(t,k,c)] padded ----------------
__global__ __launch_bounds__(256) void wcvt_kernel(const float* __restrict__ w2,
                                                   short* __restrict__ wb,
                                                   int CIN, int COUT, int CPAD, int LOGC,
                                                   int total8) {
  const int i = blockIdx.x * 256 + threadIdx.x;
  if (i >= total8) return;
  const int q8 = i * 8;
  const int QT = CPAD * 48;
  const int o = q8 / QT;
  const int r = q8 - o * QT;
  const int kq = r >> LOGC;
  const int c0 = r & (CPAD - 1);
  const int tt = kq >> 4;
  const int k = kq & 15;
  short h[8];
#pragma unroll
  for (int j = 0; j < 8; ++j) {
    const int c = c0 + j;
    const float v = (o < COUT && c < CIN) ? w2[(size_t)o * CIN * 48 + (c * 3 + tt) * 16 + k] : 0.0f;
    h[j] = f2h(v);
  }
  short* d = wb + (size_t)o * QT + r;
#pragma unroll
  for (int j = 0; j < 8; ++j) d[j] = h[j];
}

// ---------------- tay_g[l][t*16+k][p] = (w1_l @ taylor(rel) + b1_l) ----------------
__global__ __launch_bounds__(256) void taylor_kernel(
    const float* __restrict__ pc, const int* __restrict__ idx,
    const float* __restrict__ w1_1, const float* __restrict__ b1_1,
    const float* __restrict__ w1_2, const float* __restrict__ b1_2,
    const float* __restrict__ w1_3, const float* __restrict__ b1_3,
    const float* __restrict__ w1_4, const float* __restrict__ b1_4,
    float* __restrict__ tayg) {
  const int i = blockIdx.x * 256 + threadIdx.x;  // p fastest, then k
  if (i >= NPTS * KK) return;
  const int p = i & (NPTS - 1);
  const int k = i >> 14;
  const int n = p & (NN - 1);
  const int b = p >> 12;
  const float* pcb = pc + (size_t)b * NN * 6;
  const int m = idx[(size_t)p * KK + k];
  const float x = pcb[m * 6 + 0] - pcb[n * 6 + 0];
  const float y = pcb[m * 6 + 1] - pcb[n * 6 + 1];
  const float z = pcb[m * 6 + 2] - pcb[n * 6 + 2];
  float tb[20];
  tb[0] = 1.0f; tb[1] = x; tb[2] = y; tb[3] = z;
  tb[4] = x * x; tb[5] = x * y; tb[6] = x * z;
  tb[7] = y * y; tb[8] = y * z; tb[9] = z * z;
  tb[10] = tb[4] * x; tb[11] = tb[4] * y; tb[12] = tb[4] * z;
  tb[13] = tb[5] * y; tb[14] = tb[5] * z; tb[15] = tb[6] * z;
  tb[16] = tb[7] * y; tb[17] = tb[7] * z; tb[18] = tb[8] * z; tb[19] = tb[9] * z;
  const float* w1s[4] = {w1_1, w1_2, w1_3, w1_4};
  const float* b1s[4] = {b1_1, b1_2, b1_3, b1_4};
#pragma unroll
  for (int l = 0; l < 4; ++l) {
    const float* w1 = w1s[l];
    const float* b1 = b1s[l];
#pragma unroll
    for (int c = 0; c < 3; ++c) {
      float s = b1[c];
#pragma unroll
      for (int j = 0; j < 20; ++j) s = fmaf(w1[c * 20 + j], tb[j], s);
      tayg[(size_t)(l * 48 + c * 16 + k) * NPTS + p] = s;
    }
  }
}

// ---------------- spider conv via f16 MFMA; q=(t,k,c) c-fastest ----------------
template <int CPAD, int LOGC, int COUT, int OTILE>
__global__ __launch_bounds__(256) void conv_mfma_kernel(
    const char* __restrict__ ftin,        // f16 [NPTS][CPAD]
    const short* __restrict__ wb,         // f16 [OPAD][QTOT] permuted
    const float* __restrict__ b2,
    const float* __restrict__ tayg,       // f32 [48][NPTS] (this layer)
    const int* __restrict__ idx,
    float* __restrict__ pfout, int pfbstride,
    short* __restrict__ ftout, int CPADN) {
  constexpr int QTOT = CPAD * 48;
  constexpr int STEPS = QTOT / 32;
  constexpr int NJ = OTILE / 64;  // 2 (OTILE=128) or 1 (OTILE=64)
  constexpr int PW = 16 * NJ;
  __shared__ __align__(16) short As[2][OTILE * 32];
  __shared__ __align__(16) short Bs[2][64 * 32];
  __shared__ __align__(16) float tayS[48 * 64];
  __shared__ int idxS[16 * 64];
  const int t = threadIdx.x;
  const int pbase = blockIdx.x * 64;
  const int obase = blockIdx.y * OTILE;
  const int b = pbase >> 12;
  const int nbase = pbase & (NN - 1);
  const int p_loc = t >> 2;
  const int sub = t & 3;
#pragma unroll
  for (int i = 0; i < 3; ++i) {
    const int f = i * 1024 + t * 4;
    *(float4*)&tayS[f] = *(const float4*)&tayg[(size_t)(f >> 6) * NPTS + pbase + (f & 63)];
  }
  {
    const int4 mi = *(const int4*)&idx[(size_t)(pbase + p_loc) * KK + sub * 4];
    const int gb = b << 12;
    idxS[(sub * 4 + 0) * 64 + p_loc] = (gb + mi.x) << (LOGC + 1);
    idxS[(sub * 4 + 1) * 64 + p_loc] = (gb + mi.y) << (LOGC + 1);
    idxS[(sub * 4 + 2) * 64 + p_loc] = (gb + mi.z) << (LOGC + 1);
    idxS[(sub * 4 + 3) * 64 + p_loc] = (gb + mi.w) << (LOGC + 1);
  }
  const int lane = t & 63;
  const int w = t >> 6;
  const int wm = (NJ == 2) ? (w & 1) : 0;
  const int wn = (NJ == 2) ? (w >> 1) : w;
  const int fr = lane & 15;
  const int fk = lane >> 4;
  const short* aw = wb + (size_t)(obase + p_loc) * QTOT + sub * 8;
  f32x4 acc[4][NJ];
#pragma unroll
  for (int i = 0; i < 4; ++i)
#pragma unroll
    for (int j = 0; j < NJ; ++j) acc[i][j] = (f32x4)(0.0f);
  __syncthreads();  // tayS, idxS ready

  uint4 fv[2];
  float tv[2];
  auto pref = [&](int ss, int slot) {
    const int seg = ss * 32 + sub * 8;
    const int kq = seg >> LOGC;
    const int c0 = seg & (CPAD - 1);
    const int moff = idxS[(kq & 15) * 64 + p_loc];
    tv[slot] = tayS[kq * 64 + p_loc];
    fv[slot] = *(const uint4*)(ftin + moff + (c0 << 1));
  };
  auto build = [&](int slot, int dstph) {
    const __half2 t2 = __half2half2(__float2half_rn(tv[slot]));
    const uint4 f = fv[slot];
    uint4 r;
    r.x = mulh2(f.x, t2); r.y = mulh2(f.y, t2);
    r.z = mulh2(f.z, t2); r.w = mulh2(f.w, t2);
    const int chunk = sub ^ ((p_loc >> 1) & 3);
    *(uint4*)&Bs[dstph][p_loc * 32 + chunk * 8] = r;
  };
  auto dmaA = [&](int ss, int dstph) {
#pragma unroll
    for (int h = 0; h < NJ; ++h)
      __builtin_amdgcn_global_load_lds(
          (const __attribute__((address_space(1))) u32*)(aw + (size_t)h * 64 * QTOT + ss * 32),
          (__attribute__((address_space(3))) u32*)&As[dstph][h * 2048 + t * 8], 16, 0, 0);
  };
  pref(0, 0);
  dmaA(0, 0);
  pref(1, 1);
  build(0, 0);
  __syncthreads();
#pragma unroll 2
  for (int s = 0; s < STEPS; ++s) {
    const int ph = s & 1;
    if (s + 2 < STEPS) pref(s + 2, s & 1);
    if (s + 1 < STEPS) dmaA(s + 1, ph ^ 1);
    f16x8 af[4];
#pragma unroll
    for (int i = 0; i < 4; ++i)
      af[i] = *(const f16x8*)&As[ph][(wm * 64 + i * 16 + fr) * 32 + fk * 8];
    f16x8 bfr[NJ];
    const int bch = (fk ^ ((fr >> 1) & 3)) * 8;
#pragma unroll
    for (int j = 0; j < NJ; ++j)
      bfr[j] = *(const f16x8*)&Bs[ph][(wn * PW + j * 16 + fr) * 32 + bch];
    if (s + 1 < STEPS) build((s + 1) & 1, ph ^ 1);
#pragma unroll
    for (int i = 0; i < 4; ++i)
#pragma unroll
      for (int j = 0; j < NJ; ++j)
        acc[i][j] = __builtin_amdgcn_mfma_f32_16x16x32_f16(af[i], bfr[j], acc[i][j], 0, 0, 0);
    if (s + 1 < STEPS) __syncthreads();
  }
  float* outb = pfout + (size_t)b * pfbstride;
#pragma unroll
  for (int i = 0; i < 4; ++i) {
    const int o0 = obase + wm * 64 + i * 16 + fk * 4;
    if (o0 < COUT) {
      const float4 b4 = *(const float4*)&b2[o0];
#pragma unroll
      for (int j = 0; j < NJ; ++j) {
        const int p_l = wn * PW + j * 16 + fr;
        const float v0 = fmaxf(acc[i][j][0] + b4.x, 0.0f);
        const float v1 = fmaxf(acc[i][j][1] + b4.y, 0.0f);
        const float v2 = fmaxf(acc[i][j][2] + b4.z, 0.0f);
        const float v3 = fmaxf(acc[i][j][3] + b4.w, 0.0f);
        outb[(size_t)(o0 + 0) * NN + nbase + p_l] = v0;
        outb[(size_t)(o0 + 1) * NN + nbase + p_l] = v1;
        outb[(size_t)(o0 + 2) * NN + nbase + p_l] = v2;
        outb[(size_t)(o0 + 3) * NN + nbase + p_l] = v3;
        if (ftout) {
          const __half2 h01 = __floats2half2_rn(v0, v1);
          const __half2 h23 = __floats2half2_rn(v2, v3);
          uint2 pk;
          pk.x = *(const u32*)&h01;
          pk.y = *(const u32*)&h23;
          *(uint2*)&ftout[(size_t)(pbase + p_l) * CPADN + o0] = pk;
        }
      }
    }
  }
}

// ---------------- top-2 over N per (b, channel) ----------------
__global__ __launch_bounds__(256) void top2_kernel(const float* __restrict__ pf,
                                                   float* __restrict__ cat) {
  const int row = blockIdx.x;  // b*480 + ch
  const float* p = pf + (size_t)row * NN;
  float m1 = -FLT_MAX, m2 = -FLT_MAX;
  for (int i = threadIdx.x; i < NN; i += 256) {
    const float v = p[i];
    if (v > m1) { m2 = m1; m1 = v; }
    else if (v > m2) m2 = v;
  }
#pragma unroll
  for (int off = 32; off > 0; off >>= 1) {
    const float o1 = __shfl_down(m1, off, 64);
    const float o2 = __shfl_down(m2, off, 64);
    const float nm1 = fmaxf(m1, o1);
    const float nm2 = fmaxf(fminf(m1, o1), fmaxf(m2, o2));
    m1 = nm1; m2 = nm2;
  }
  __shared__ float s1[4], s2[4];
  const int wid = threadIdx.x >> 6;
  if ((threadIdx.x & 63) == 0) { s1[wid] = m1; s2[wid] = m2; }
  __syncthreads();
  if (threadIdx.x == 0) {
    m1 = s1[0]; m2 = s2[0];
#pragma unroll
    for (int w = 1; w < 4; ++w) {
      const float o1 = s1[w], o2 = s2[w];
      const float nm1 = fmaxf(m1, o1);
      const float nm2 = fmaxf(fminf(m1, o1), fmaxf(m2, o2));
      m1 = nm1; m2 = nm2;
    }
    const int b = row / 480, ch = row % 480;
    cat[b * 960 + ch * 2 + 0] = m1;
    cat[b * 960 + ch * 2 + 1] = m2;
  }
}

extern "C" void kernel_launch(void* const* d_in, const int* in_sizes, int n_in,
                              void* d_out, int out_size, void* d_ws, size_t ws_size,
                              hipStream_t stream) {
  const float* pc = (const float*)d_in[0];
  const float* w1s[4]; const float* b1s[4]; const float* w2s[4]; const float* b2s[4];
  for (int l = 0; l < 4; ++l) {
    w1s[l] = (const float*)d_in[1 + 4 * l];
    b1s[l] = (const float*)d_in[2 + 4 * l];
    w2s[l] = (const float*)d_in[3 + 4 * l];
    b2s[l] = (const float*)d_in[4 + 4 * l];
  }
  // ---- workspace layout (bytes) ----
  char* W = (char*)d_ws;
  int* idx = (int*)W;                                  // 1,048,576
  float* tayg = (float*)(W + 1048576);                 // 4 x 3,145,728 = 12,582,912
  short* wb1 = (short*)(W + 13631488);                 // 64*384    f16 =    49,152 B
  short* wb2 = wb1 + 64 * 384;                         // 64*1536       =   196,608 B
  short* wb3 = wb2 + 64 * 1536;                        // 128*3072      =   786,432 B
  short* wb4 = wb3 + 128 * 3072;                       // 256*6144      = 3,145,728 B
  short* ft0 = (short*)(W + 17809408);                 // 16384*8  f16  =   262,144 B
  short* ft1 = (short*)(W + 18071552);                 // 16384*32      = 1,048,576 B
  // knn-phase aliases (consumed before their regions are rewritten):
  float* partd = tayg;                                 // 16K*8*16*4B = 4 MB, in tayg[0..]
  float* candd = tayg + 1048576;                       // 16K*64*4B = 4 MB
  int* candi = (int*)(tayg + 2097152);                 // 4 MB
  float* Tthr = (float*)wb1;                           // 64 KB, in wb1/wb2 region
  int* cnt = (int*)wb1 + 16384;                        // 64 KB
  // conv-phase aliases:
  short* ft2 = (short*)(W + 1048576);                  // 2 MB in tayg[0]; written L2-epi
  short* ft3 = (short*)(W + 1048576 + 2097152);        // 4 MB; written L3-epi
  float* cat = (float*)d_out;                          // B*960
  float* pf = (float*)d_out + BB * 960;                // (B, 480, N)
  const int pfstride = 480 * NN;

  knn_part_vals<<<dim3(NN / 256, BB, 8), 256, 0, stream>>>(pc, partd);
  knn_merge_vals<<<dim3(NPTS / 256), 256, 0, stream>>>(partd, Tthr, cnt);
  knn_collect<<<dim3(NN / 256, BB, 8), 256, 0, stream>>>(pc, Tthr, cnt, candd, candi);
  knn_sort16<<<dim3(NPTS / 256), 256, 0, stream>>>(candd, candi, cnt, idx);
  pc2ft_kernel<<<dim3(NPTS / 256), 256, 0, stream>>>(pc, ft0);
  wcvt_kernel<<<dim3((64 * 384 / 8 + 255) / 256), 256, 0, stream>>>(w2s[0], wb1, 6, 32, 8, 3, 64 * 384 / 8);
  wcvt_kernel<<<dim3((64 * 1536 / 8 + 255) / 256), 256, 0, stream>>>(w2s[1], wb2, 32, 64, 32, 5, 64 * 1536 / 8);
  wcvt_kernel<<<dim3((128 * 3072 / 8 + 255) / 256), 256, 0, stream>>>(w2s[2], wb3, 64, 128, 64, 6, 128 * 3072 / 8);
  wcvt_kernel<<<dim3((256 * 6144 / 8 + 255) / 256), 256, 0, stream>>>(w2s[3], wb4, 128, 256, 128, 7, 256 * 6144 / 8);
  taylor_kernel<<<dim3(NPTS * KK / 256), 256, 0, stream>>>(
      pc, idx, w1s[0], b1s[0], w1s[1], b1s[1], w1s[2], b1s[2], w1s[3], b1s[3], tayg);
  conv_mfma_kernel<8, 3, 32, 64><<<dim3(NPTS / 64, 1), 256, 0, stream>>>(
      (const char*)ft0, wb1, b2s[0], tayg + 0 * (size_t)NT48, idx,
      pf + (size_t)0 * NN, pfstride, ft1, 32);
  conv_mfma_kernel<32, 5, 64, 64><<<dim3(NPTS / 64, 1), 256, 0, stream>>>(
      (const char*)ft1, wb2, b2s[1], tayg + 1 * (size_t)NT48, idx,
      pf + (size_t)32 * NN, pfstride, ft2, 64);
  conv_mfma_kernel<64, 6, 128, 64><<<dim3(NPTS / 64, 2), 256, 0, stream>>>(
      (const char*)ft2, wb3, b2s[2], tayg + 2 * (size_t)NT48, idx,
      pf + (size_t)96 * NN, pfstride, ft3, 128);
  conv_mfma_kernel<128, 7, 256, 128><<<dim3(NPTS / 64, 2), 256, 0, stream>>>(
      (const char*)ft3, wb4, b2s[3], tayg + 3 * (size_t)NT48, idx,
      pf + (size_t)224 * NN, pfstride, nullptr, 0);
  top2_kernel<<<dim3(BB * 480), 256, 0, stream>>>(pf, cat);
}

// Round 5
// 504.322 us; speedup vs baseline: 1.4013x; 1.4013x over previous
//
#include <hip/hip_runtime.h>
#include <hip/hip_fp16.h>
#include <cfloat>

#define BB 4
#define NN 4096
#define KK 16
#define NPTS (BB * NN)      // 16384
#define NT48 (48 * NPTS)    // per-layer tay floats, layout [48][NPTS]

typedef __attribute__((ext_vector_type(8))) _Float16 f16x8;
typedef __attribute__((ext_vector_type(4))) float f32x4;
typedef unsigned int u32;
typedef unsigned long long u64;

__device__ __forceinline__ short f2h(float v) {
  __half h = __float2half_rn(v);
  return __half_as_short(h);
}
__device__ __forceinline__ u32 mulh2(u32 a, __half2 t) {
  __half2 x = __hmul2(*(__half2*)&a, t);
  return *(u32*)&x;
}

// ---------------- pc -> ft0 f16 [p][8] + xyzq f32 [p][4] ----------------
__global__ __launch_bounds__(256) void pc2ft_kernel(const float* __restrict__ pc,
                                                    short* __restrict__ ft0,
                                                    float4* __restrict__ xyzq) {
  const int i = blockIdx.x * 256 + threadIdx.x;
  if (i >= NPTS) return;
  const float* s = pc + (size_t)i * 6;
  short* d = ft0 + (size_t)i * 8;
#pragma unroll
  for (int c = 0; c < 6; ++c) d[c] = f2h(s[c]);
  d[6] = 0; d[7] = 0;
  const float x = s[0], y = s[1], z = s[2];
  xyzq[i] = make_float4(x, y, z, fmaf(z, z, fmaf(y, y, x * x)));
}

// ---------------- KNN: 2-round radix select, one block per query ----------------
// Exact top-16 by (d2, idx) lexicographic (== jax top_k tie semantics).
// Keys live in registers end-to-end; no insertion chain.
__global__ __launch_bounds__(256) void knn_select(const float4* __restrict__ xyzq,
                                                  int* __restrict__ idx_out) {
  __shared__ u32 hist[256];
  __shared__ u32 wsum[4];
  __shared__ u32 sb1, sbelow1, sb2;
  __shared__ u64 list[64];
  __shared__ int lcnt;
  const int g = blockIdx.x;   // query point (b*4096 + n)
  const int b = g >> 12;
  const int t = threadIdx.x;
  const float4* base = xyzq + (b << 12);
  const float4 q = xyzq[g];
  u32 key[16];
#pragma unroll
  for (int i = 0; i < 16; ++i) {
    const float4 c = base[i * 256 + t];
    const float dot = fmaf(q.z, c.z, fmaf(q.y, c.y, q.x * c.x));
    const float d2 = fmaf(-2.0f, dot, q.w + c.w);
    const u32 bits = __float_as_uint(d2);
    key[i] = bits ^ ((u32)((int)bits >> 31) | 0x80000000u);  // monotonic total order
  }
  hist[t] = 0;
  if (t == 0) lcnt = 0;
  __syncthreads();  // B1
#pragma unroll
  for (int i = 0; i < 16; ++i) atomicAdd(&hist[key[i] >> 24], 1u);
  __syncthreads();  // B2
  // ---- scan 1: find bucket b1 where cumulative count crosses 16 ----
  u32 h = hist[t];
  u32 inc = h;
#pragma unroll
  for (int off = 1; off < 64; off <<= 1) {
    const u32 up = __shfl_up(inc, off, 64);
    if ((t & 63) >= off) inc += up;
  }
  if ((t & 63) == 63) wsum[t >> 6] = inc;
  __syncthreads();  // B3
  u32 excl = inc - h;
  for (int wv = 0; wv < (t >> 6); ++wv) excl += wsum[wv];
  if (excl < 16u && excl + h >= 16u) { sb1 = t; sbelow1 = excl; }
  __syncthreads();  // B4
  const u32 b1 = sb1;
  const u32 below1 = sbelow1;
  hist[t] = 0;
  __syncthreads();  // B5
  // ---- round 2 within bucket b1 ----
#pragma unroll
  for (int i = 0; i < 16; ++i)
    if ((key[i] >> 24) == b1) atomicAdd(&hist[(key[i] >> 16) & 0xFFu], 1u);
  __syncthreads();  // B6
  h = hist[t];
  inc = h;
#pragma unroll
  for (int off = 1; off < 64; off <<= 1) {
    const u32 up = __shfl_up(inc, off, 64);
    if ((t & 63) >= off) inc += up;
  }
  if ((t & 63) == 63) wsum[t >> 6] = inc;
  __syncthreads();  // B7
  excl = inc - h;
  for (int wv = 0; wv < (t >> 6); ++wv) excl += wsum[wv];
  const u32 r2 = 16u - below1;
  if (excl < r2 && excl + h >= r2) sb2 = t;
  __syncthreads();  // B8
  const u32 P = (b1 << 8) | sb2;  // 16-bit prefix of the rank-16 key
  // ---- collect all candidates with key-prefix <= P (superset of true top-16) ----
#pragma unroll
  for (int i = 0; i < 16; ++i) {
    if ((key[i] >> 16) <= P) {
      const int pos = atomicAdd(&lcnt, 1);
      if (pos < 64) list[pos] = ((u64)key[i] << 32) | (u32)(i * 256 + t);
    }
  }
  __syncthreads();  // B9
  // ---- wave 0: extract 16 smallest u64 (d2, idx) in order ----
  if (t < 64) {
    const int m = min(lcnt, 64);
    u64 my = (t < m) ? list[t] : ~0ull;
    int* out = idx_out + (size_t)g * KK;
    for (int o = 0; o < 16; ++o) {
      u64 v = my;
#pragma unroll
      for (int off = 32; off > 0; off >>= 1) {
        const u64 w = (u64)__shfl_xor((long long)v, off, 64);
        v = (w < v) ? w : v;
      }
      if (my == v) my = ~0ull;  // unique (distinct idx in low bits)
      if (t == 0) out[o] = (int)(v & 0xFFFFFFFFull);
    }
  }
}

// ---------------- weights fp32 (o,(c,t),k) -> f16 permuted [o][(t,k,c)] padded ----------------
__global__ __launch_bounds__(256) void wcvt_kernel(const float* __restrict__ w2,
                                                   short* __restrict__ wb,
                                                   int CIN, int COUT, int CPAD, int LOGC,
                                                   int total8) {
  const int i = blockIdx.x * 256 + threadIdx.x;
  if (i >= total8) return;
  const int q8 = i * 8;
  const int QT = CPAD * 48;
  const int o = q8 / QT;
  const int r = q8 - o * QT;
  const int kq = r >> LOGC;
  const int c0 = r & (CPAD - 1);
  const int tt = kq >> 4;
  const int k = kq & 15;
  short h[8];
#pragma unroll
  for (int j = 0; j < 8; ++j) {
    const int c = c0 + j;
    const float v = (o < COUT && c < CIN) ? w2[(size_t)o * CIN * 48 + (c * 3 + tt) * 16 + k] : 0.0f;
    h[j] = f2h(v);
  }
  short* d = wb + (size_t)o * QT + r;
#pragma unroll
  for (int j = 0; j < 8; ++j) d[j] = h[j];
}

// ---------------- tay_g[l][t*16+k][p] = (w1_l @ taylor(rel) + b1_l) ----------------
__global__ __launch_bounds__(256) void taylor_kernel(
    const float* __restrict__ pc, const int* __restrict__ idx,
    const float* __restrict__ w1_1, const float* __restrict__ b1_1,
    const float* __restrict__ w1_2, const float* __restrict__ b1_2,
    const float* __restrict__ w1_3, const float* __restrict__ b1_3,
    const float* __restrict__ w1_4, const float* __restrict__ b1_4,
    float* __restrict__ tayg) {
  const int i = blockIdx.x * 256 + threadIdx.x;  // p fastest, then k
  if (i >= NPTS * KK) return;
  const int p = i & (NPTS - 1);
  const int k = i >> 14;
  const int n = p & (NN - 1);
  const int b = p >> 12;
  const float* pcb = pc + (size_t)b * NN * 6;
  const int m = idx[(size_t)p * KK + k];
  const float x = pcb[m * 6 + 0] - pcb[n * 6 + 0];
  const float y = pcb[m * 6 + 1] - pcb[n * 6 + 1];
  const float z = pcb[m * 6 + 2] - pcb[n * 6 + 2];
  float tb[20];
  tb[0] = 1.0f; tb[1] = x; tb[2] = y; tb[3] = z;
  tb[4] = x * x; tb[5] = x * y; tb[6] = x * z;
  tb[7] = y * y; tb[8] = y * z; tb[9] = z * z;
  tb[10] = tb[4] * x; tb[11] = tb[4] * y; tb[12] = tb[4] * z;
  tb[13] = tb[5] * y; tb[14] = tb[5] * z; tb[15] = tb[6] * z;
  tb[16] = tb[7] * y; tb[17] = tb[7] * z; tb[18] = tb[8] * z; tb[19] = tb[9] * z;
  const float* w1s[4] = {w1_1, w1_2, w1_3, w1_4};
  const float* b1s[4] = {b1_1, b1_2, b1_3, b1_4};
#pragma unroll
  for (int l = 0; l < 4; ++l) {
    const float* w1 = w1s[l];
    const float* b1 = b1s[l];
#pragma unroll
    for (int c = 0; c < 3; ++c) {
      float s = b1[c];
#pragma unroll
      for (int j = 0; j < 20; ++j) s = fmaf(w1[c * 20 + j], tb[j], s);
      tayg[(size_t)(l * 48 + c * 16 + k) * NPTS + p] = s;
    }
  }
}

// ---------------- spider conv via f16 MFMA; q=(t,k,c) c-fastest ----------------
template <int CPAD, int LOGC, int COUT, int OTILE>
__global__ __launch_bounds__(256) void conv_mfma_kernel(
    const char* __restrict__ ftin,        // f16 [NPTS][CPAD]
    const short* __restrict__ wb,         // f16 [OPAD][QTOT] permuted
    const float* __restrict__ b2,
    const float* __restrict__ tayg,       // f32 [48][NPTS] (this layer)
    const int* __restrict__ idx,
    float* __restrict__ pfout, int pfbstride,
    short* __restrict__ ftout, int CPADN) {
  constexpr int QTOT = CPAD * 48;
  constexpr int STEPS = QTOT / 32;
  constexpr int NJ = OTILE / 64;  // 2 (OTILE=128) or 1 (OTILE=64)
  constexpr int PW = 16 * NJ;
  __shared__ __align__(16) short As[2][OTILE * 32];
  __shared__ __align__(16) short Bs[2][64 * 32];
  __shared__ __align__(16) float tayS[48 * 64];
  __shared__ int idxS[16 * 64];
  const int t = threadIdx.x;
  const int pbase = blockIdx.x * 64;
  const int obase = blockIdx.y * OTILE;
  const int b = pbase >> 12;
  const int nbase = pbase & (NN - 1);
  const int p_loc = t >> 2;
  const int sub = t & 3;
#pragma unroll
  for (int i = 0; i < 3; ++i) {
    const int f = i * 1024 + t * 4;
    *(float4*)&tayS[f] = *(const float4*)&tayg[(size_t)(f >> 6) * NPTS + pbase + (f & 63)];
  }
  {
    const int4 mi = *(const int4*)&idx[(size_t)(pbase + p_loc) * KK + sub * 4];
    const int gb = b << 12;
    idxS[(sub * 4 + 0) * 64 + p_loc] = (gb + mi.x) << (LOGC + 1);
    idxS[(sub * 4 + 1) * 64 + p_loc] = (gb + mi.y) << (LOGC + 1);
    idxS[(sub * 4 + 2) * 64 + p_loc] = (gb + mi.z) << (LOGC + 1);
    idxS[(sub * 4 + 3) * 64 + p_loc] = (gb + mi.w) << (LOGC + 1);
  }
  const int lane = t & 63;
  const int w = t >> 6;
  const int wm = (NJ == 2) ? (w & 1) : 0;
  const int wn = (NJ == 2) ? (w >> 1) : w;
  const int fr = lane & 15;
  const int fk = lane >> 4;
  const short* aw = wb + (size_t)(obase + p_loc) * QTOT + sub * 8;
  f32x4 acc[4][NJ];
#pragma unroll
  for (int i = 0; i < 4; ++i)
#pragma unroll
    for (int j = 0; j < NJ; ++j) acc[i][j] = (f32x4)(0.0f);
  __syncthreads();  // tayS, idxS ready

  uint4 fv[2];
  float tv[2];
  auto pref = [&](int ss, int slot) {
    const int seg = ss * 32 + sub * 8;
    const int kq = seg >> LOGC;
    const int c0 = seg & (CPAD - 1);
    const int moff = idxS[(kq & 15) * 64 + p_loc];
    tv[slot] = tayS[kq * 64 + p_loc];
    fv[slot] = *(const uint4*)(ftin + moff + (c0 << 1));
  };
  auto build = [&](int slot, int dstph) {
    const __half2 t2 = __half2half2(__float2half_rn(tv[slot]));
    const uint4 f = fv[slot];
    uint4 r;
    r.x = mulh2(f.x, t2); r.y = mulh2(f.y, t2);
    r.z = mulh2(f.z, t2); r.w = mulh2(f.w, t2);
    const int chunk = sub ^ ((p_loc >> 1) & 3);
    *(uint4*)&Bs[dstph][p_loc * 32 + chunk * 8] = r;
  };
  auto dmaA = [&](int ss, int dstph) {
#pragma unroll
    for (int h = 0; h < NJ; ++h)
      __builtin_amdgcn_global_load_lds(
          (const __attribute__((address_space(1))) u32*)(aw + (size_t)h * 64 * QTOT + ss * 32),
          (__attribute__((address_space(3))) u32*)&As[dstph][h * 2048 + t * 8], 16, 0, 0);
  };
  pref(0, 0);
  dmaA(0, 0);
  pref(1, 1);
  build(0, 0);
  __syncthreads();
#pragma unroll 2
  for (int s = 0; s < STEPS; ++s) {
    const int ph = s & 1;
    if (s + 2 < STEPS) pref(s + 2, s & 1);
    if (s + 1 < STEPS) dmaA(s + 1, ph ^ 1);
    f16x8 af[4];
#pragma unroll
    for (int i = 0; i < 4; ++i)
      af[i] = *(const f16x8*)&As[ph][(wm * 64 + i * 16 + fr) * 32 + fk * 8];
    f16x8 bfr[NJ];
    const int bch = (fk ^ ((fr >> 1) & 3)) * 8;
#pragma unroll
    for (int j = 0; j < NJ; ++j)
      bfr[j] = *(const f16x8*)&Bs[ph][(wn * PW + j * 16 + fr) * 32 + bch];
    if (s + 1 < STEPS) build((s + 1) & 1, ph ^ 1);
#pragma unroll
    for (int i = 0; i < 4; ++i)
#pragma unroll
      for (int j = 0; j < NJ; ++j)
        acc[i][j] = __builtin_amdgcn_mfma_f32_16x16x32_f16(af[i], bfr[j], acc[i][j], 0, 0, 0);
    if (s + 1 < STEPS) __syncthreads();
  }
  float* outb = pfout + (size_t)b * pfbstride;
#pragma unroll
  for (int i = 0; i < 4; ++i) {
    const int o0 = obase + wm * 64 + i * 16 + fk * 4;
    if (o0 < COUT) {
      const float4 b4 = *(const float4*)&b2[o0];
#pragma unroll
      for (int j = 0; j < NJ; ++j) {
        const int p_l = wn * PW + j * 16 + fr;
        const float v0 = fmaxf(acc[i][j][0] + b4.x, 0.0f);
        const float v1 = fmaxf(acc[i][j][1] + b4.y, 0.0f);
        const float v2 = fmaxf(acc[i][j][2] + b4.z, 0.0f);
        const float v3 = fmaxf(acc[i][j][3] + b4.w, 0.0f);
        outb[(size_t)(o0 + 0) * NN + nbase + p_l] = v0;
        outb[(size_t)(o0 + 1) * NN + nbase + p_l] = v1;
        outb[(size_t)(o0 + 2) * NN + nbase + p_l] = v2;
        outb[(size_t)(o0 + 3) * NN + nbase + p_l] = v3;
        if (ftout) {
          const __half2 h01 = __floats2half2_rn(v0, v1);
          const __half2 h23 = __floats2half2_rn(v2, v3);
          uint2 pk;
          pk.x = *(const u32*)&h01;
          pk.y = *(const u32*)&h23;
          *(uint2*)&ftout[(size_t)(pbase + p_l) * CPADN + o0] = pk;
        }
      }
    }
  }
}

// ---------------- top-2 over N per (b, channel) ----------------
__global__ __launch_bounds__(256) void top2_kernel(const float* __restrict__ pf,
                                                   float* __restrict__ cat) {
  const int row = blockIdx.x;  // b*480 + ch
  const float* p = pf + (size_t)row * NN;
  float m1 = -FLT_MAX, m2 = -FLT_MAX;
  for (int i = threadIdx.x; i < NN; i += 256) {
    const float v = p[i];
    if (v > m1) { m2 = m1; m1 = v; }
    else if (v > m2) m2 = v;
  }
#pragma unroll
  for (int off = 32; off > 0; off >>= 1) {
    const float o1 = __shfl_down(m1, off, 64);
    const float o2 = __shfl_down(m2, off, 64);
    const float nm1 = fmaxf(m1, o1);
    const float nm2 = fmaxf(fminf(m1, o1), fmaxf(m2, o2));
    m1 = nm1; m2 = nm2;
  }
  __shared__ float s1[4], s2[4];
  const int wid = threadIdx.x >> 6;
  if ((threadIdx.x & 63) == 0) { s1[wid] = m1; s2[wid] = m2; }
  __syncthreads();
  if (threadIdx.x == 0) {
    m1 = s1[0]; m2 = s2[0];
#pragma unroll
    for (int w = 1; w < 4; ++w) {
      const float o1 = s1[w], o2 = s2[w];
      const float nm1 = fmaxf(m1, o1);
      const float nm2 = fmaxf(fminf(m1, o1), fmaxf(m2, o2));
      m1 = nm1; m2 = nm2;
    }
    const int b = row / 480, ch = row % 480;
    cat[b * 960 + ch * 2 + 0] = m1;
    cat[b * 960 + ch * 2 + 1] = m2;
  }
}

extern "C" void kernel_launch(void* const* d_in, const int* in_sizes, int n_in,
                              void* d_out, int out_size, void* d_ws, size_t ws_size,
                              hipStream_t stream) {
  const float* pc = (const float*)d_in[0];
  const float* w1s[4]; const float* b1s[4]; const float* w2s[4]; const float* b2s[4];
  for (int l = 0; l < 4; ++l) {
    w1s[l] = (const float*)d_in[1 + 4 * l];
    b1s[l] = (const float*)d_in[2 + 4 * l];
    w2s[l] = (const float*)d_in[3 + 4 * l];
    b2s[l] = (const float*)d_in[4 + 4 * l];
  }
  // ---- workspace layout (bytes) ----
  char* W = (char*)d_ws;
  int* idx = (int*)W;                                  // 1,048,576
  float* tayg = (float*)(W + 1048576);                 // 4 x 3,145,728 = 12,582,912
  short* wb1 = (short*)(W + 13631488);                 // 64*384    f16 =    49,152 B
  short* wb2 = wb1 + 64 * 384;                         // 64*1536       =   196,608 B
  short* wb3 = wb2 + 64 * 1536;                        // 128*3072      =   786,432 B
  short* wb4 = wb3 + 128 * 3072;                       // 256*6144      = 3,145,728 B
  short* ft0 = (short*)(W + 17809408);                 // 16384*8  f16  =   262,144 B
  short* ft1 = (short*)(W + 18071552);                 // 16384*32      = 1,048,576 B
  // knn-phase alias (consumed before tayg is written):
  float4* xyzq = (float4*)(W + 1048576);               // 16384*16 B = 262,144, in tayg[0]
  // conv-phase aliases:
  short* ft2 = (short*)(W + 1048576);                  // 2 MB in tayg[0]; written L2-epi (tayg[0] row range dead? no - ft2 written during L2 conv epilogue, tayg[0] consumed by L1 conv already)
  short* ft3 = (short*)(W + 1048576 + 2097152);        // 4 MB; written L3-epi
  float* cat = (float*)d_out;                          // B*960
  float* pf = (float*)d_out + BB * 960;                // (B, 480, N)
  const int pfstride = 480 * NN;

  pc2ft_kernel<<<dim3(NPTS / 256), 256, 0, stream>>>(pc, ft0, xyzq);
  knn_select<<<dim3(NPTS), 256, 0, stream>>>(xyzq, idx);
  wcvt_kernel<<<dim3((64 * 384 / 8 + 255) / 256), 256, 0, stream>>>(w2s[0], wb1, 6, 32, 8, 3, 64 * 384 / 8);
  wcvt_kernel<<<dim3((64 * 1536 / 8 + 255) / 256), 256, 0, stream>>>(w2s[1], wb2, 32, 64, 32, 5, 64 * 1536 / 8);
  wcvt_kernel<<<dim3((128 * 3072 / 8 + 255) / 256), 256, 0, stream>>>(w2s[2], wb3, 64, 128, 64, 6, 128 * 3072 / 8);
  wcvt_kernel<<<dim3((256 * 6144 / 8 + 255) / 256), 256, 0, stream>>>(w2s[3], wb4, 128, 256, 128, 7, 256 * 6144 / 8);
  taylor_kernel<<<dim3(NPTS * KK / 256), 256, 0, stream>>>(
      pc, idx, w1s[0], b1s[0], w1s[1], b1s[1], w1s[2], b1s[2], w1s[3], b1s[3], tayg);
  conv_mfma_kernel<8, 3, 32, 64><<<dim3(NPTS / 64, 1), 256, 0, stream>>>(
      (const char*)ft0, wb1, b2s[0], tayg + 0 * (size_t)NT48, idx,
      pf + (size_t)0 * NN, pfstride, ft1, 32);
  conv_mfma_kernel<32, 5, 64, 64><<<dim3(NPTS / 64, 1), 256, 0, stream>>>(
      (const char*)ft1, wb2, b2s[1], tayg + 1 * (size_t)NT48, idx,
      pf + (size_t)32 * NN, pfstride, ft2, 64);
  conv_mfma_kernel<64, 6, 128, 64><<<dim3(NPTS / 64, 2), 256, 0, stream>>>(
      (const char*)ft2, wb3, b2s[2], tayg + 2 * (size_t)NT48, idx,
      pf + (size_t)96 * NN, pfstride, ft3, 128);
  conv_mfma_kernel<128, 7, 256, 128><<<dim3(NPTS / 64, 2), 256, 0, stream>>>(
      (const char*)ft3, wb4, b2s[3], tayg + 3 * (size_t)NT48, idx,
      pf + (size_t)224 * NN, pfstride, nullptr, 0);
  top2_kernel<<<dim3(BB * 480), 256, 0, stream>>>(pf, cat);
}

// Round 6
// 437.938 us; speedup vs baseline: 1.6137x; 1.1516x over previous
//
#include <hip/hip_runtime.h>
#include <hip/hip_fp16.h>
#include <cfloat>

#define BB 4
#define NN 4096
#define KK 16
#define NPTS (BB * NN)      // 16384
#define NT48 (48 * NPTS)    // per-layer tay floats, layout [48][NPTS]

typedef __attribute__((ext_vector_type(8))) _Float16 f16x8;
typedef __attribute__((ext_vector_type(4))) float f32x4;
typedef unsigned int u32;
typedef unsigned long long u64;

__device__ __forceinline__ short f2h(float v) {
  __half h = __float2half_rn(v);
  return __half_as_short(h);
}
__device__ __forceinline__ u32 mulh2(u32 a, __half2 t) {
  __half2 x = __hmul2(*(__half2*)&a, t);
  return *(u32*)&x;
}

// ---------------- pc -> ft0 f16 [p][8] + xyzq f32 [p][4] ----------------
__global__ __launch_bounds__(256) void pc2ft_kernel(const float* __restrict__ pc,
                                                    short* __restrict__ ft0,
                                                    float4* __restrict__ xyzq) {
  const int i = blockIdx.x * 256 + threadIdx.x;
  if (i >= NPTS) return;
  const float* s = pc + (size_t)i * 6;
  short* d = ft0 + (size_t)i * 8;
#pragma unroll
  for (int c = 0; c < 6; ++c) d[c] = f2h(s[c]);
  d[6] = 0; d[7] = 0;
  const float x = s[0], y = s[1], z = s[2];
  xyzq[i] = make_float4(x, y, z, fmaf(z, z, fmaf(y, y, x * x)));
}

// ---------------- KNN: min-threshold select, one block per query ----------------
// Exact top-16 by (d2, idx) lexicographic (== jax top_k tie semantics).
// T = min over waves of (wave's 16th-distinct-smallest thread-min) >= true
// 16th-smallest key: at most 15 keys are < key16, so any wave has <=15
// thread-mins below key16. No histograms, no hot-path atomics.
__global__ __launch_bounds__(256) void knn_select(const float4* __restrict__ xyzq,
                                                  int* __restrict__ idx_out) {
  __shared__ u32 wT[4];
  __shared__ u64 list[128];
  __shared__ int lcnt;
  const int g = blockIdx.x;   // query point (b*4096 + n)
  const int b = g >> 12;
  const int t = threadIdx.x;
  const float4* base = xyzq + (b << 12);
  const float4 q = xyzq[g];
  u32 key[16];
  u32 mymin = 0xFFFFFFFFu;
#pragma unroll
  for (int i = 0; i < 16; ++i) {
    const float4 c = base[i * 256 + t];
    const float dot = fmaf(q.z, c.z, fmaf(q.y, c.y, q.x * c.x));
    const float d2 = fmaf(-2.0f, dot, q.w + c.w);
    const u32 bits = __float_as_uint(d2);
    key[i] = bits ^ ((u32)((int)bits >> 31) | 0x80000000u);  // monotonic total order
    mymin = min(mymin, key[i]);
  }
  if (t == 0) lcnt = 0;
  // ---- per-wave: 16th (distinct-collapsed) smallest of 64 thread-mins ----
  u32 mv = mymin, v = 0;
  for (int o = 0; o < 16; ++o) {
    v = mv;
#pragma unroll
    for (int off = 32; off > 0; off >>= 1)
      v = min(v, (u32)__shfl_xor((int)v, off, 64));
    if (mv == v) mv = 0xFFFFFFFFu;  // tie-group collapse only raises T: still safe
  }
  if ((t & 63) == 0) wT[t >> 6] = v;
  __syncthreads();
  const u32 T = min(min(wT[0], wT[1]), min(wT[2], wT[3]));
  // ---- collect all candidates with key <= T (guaranteed superset of top-16) ----
#pragma unroll
  for (int i = 0; i < 16; ++i) {
    if (key[i] <= T) {
      const int pos = atomicAdd(&lcnt, 1);
      if (pos < 128) list[pos] = ((u64)key[i] << 32) | (u32)(i * 256 + t);
    }
  }
  __syncthreads();
  // ---- wave 0: extract 16 smallest u64 (d2, idx) in order ----
  if (t < 64) {
    const int m = min(lcnt, 128);
    u64 a = (t < m) ? list[t] : ~0ull;
    u64 b2v = (t + 64 < m) ? list[t + 64] : ~0ull;
    int* out = idx_out + (size_t)g * KK;
    for (int o = 0; o < 16; ++o) {
      u64 w = (a < b2v) ? a : b2v;
#pragma unroll
      for (int off = 32; off > 0; off >>= 1) {
        const u64 s = (u64)__shfl_xor((long long)w, off, 64);
        w = (s < w) ? s : w;
      }
      if (t == 0) out[o] = (int)(w & 0xFFFFFFFFull);
      if (a == w) a = ~0ull;       // unique: distinct idx in low bits
      else if (b2v == w) b2v = ~0ull;
    }
  }
}

// ---------------- weights fp32 (o,(c,t),k) -> f16 permuted [o][(t,k,c)] padded ----------------
__global__ __launch_bounds__(256) void wcvt_kernel(const float* __restrict__ w2,
                                                   short* __restrict__ wb,
                                                   int CIN, int COUT, int CPAD, int LOGC,
                                                   int total8) {
  const int i = blockIdx.x * 256 + threadIdx.x;
  if (i >= total8) return;
  const int q8 = i * 8;
  const int QT = CPAD * 48;
  const int o = q8 / QT;
  const int r = q8 - o * QT;
  const int kq = r >> LOGC;
  const int c0 = r & (CPAD - 1);
  const int tt = kq >> 4;
  const int k = kq & 15;
  short h[8];
#pragma unroll
  for (int j = 0; j < 8; ++j) {
    const int c = c0 + j;
    const float v = (o < COUT && c < CIN) ? w2[(size_t)o * CIN * 48 + (c * 3 + tt) * 16 + k] : 0.0f;
    h[j] = f2h(v);
  }
  short* d = wb + (size_t)o * QT + r;
#pragma unroll
  for (int j = 0; j < 8; ++j) d[j] = h[j];
}

// ---------------- tay_g[l][t*16+k][p] = (w1_l @ taylor(rel) + b1_l) ----------------
__global__ __launch_bounds__(256) void taylor_kernel(
    const float* __restrict__ pc, const int* __restrict__ idx,
    const float* __restrict__ w1_1, const float* __restrict__ b1_1,
    const float* __restrict__ w1_2, const float* __restrict__ b1_2,
    const float* __restrict__ w1_3, const float* __restrict__ b1_3,
    const float* __restrict__ w1_4, const float* __restrict__ b1_4,
    float* __restrict__ tayg) {
  const int i = blockIdx.x * 256 + threadIdx.x;  // p fastest, then k
  if (i >= NPTS * KK) return;
  const int p = i & (NPTS - 1);
  const int k = i >> 14;
  const int n = p & (NN - 1);
  const int b = p >> 12;
  const float* pcb = pc + (size_t)b * NN * 6;
  const int m = idx[(size_t)p * KK + k];
  const float x = pcb[m * 6 + 0] - pcb[n * 6 + 0];
  const float y = pcb[m * 6 + 1] - pcb[n * 6 + 1];
  const float z = pcb[m * 6 + 2] - pcb[n * 6 + 2];
  float tb[20];
  tb[0] = 1.0f; tb[1] = x; tb[2] = y; tb[3] = z;
  tb[4] = x * x; tb[5] = x * y; tb[6] = x * z;
  tb[7] = y * y; tb[8] = y * z; tb[9] = z * z;
  tb[10] = tb[4] * x; tb[11] = tb[4] * y; tb[12] = tb[4] * z;
  tb[13] = tb[5] * y; tb[14] = tb[5] * z; tb[15] = tb[6] * z;
  tb[16] = tb[7] * y; tb[17] = tb[7] * z; tb[18] = tb[8] * z; tb[19] = tb[9] * z;
  const float* w1s[4] = {w1_1, w1_2, w1_3, w1_4};
  const float* b1s[4] = {b1_1, b1_2, b1_3, b1_4};
#pragma unroll
  for (int l = 0; l < 4; ++l) {
    const float* w1 = w1s[l];
    const float* b1 = b1s[l];
#pragma unroll
    for (int c = 0; c < 3; ++c) {
      float s = b1[c];
#pragma unroll
      for (int j = 0; j < 20; ++j) s = fmaf(w1[c * 20 + j], tb[j], s);
      tayg[(size_t)(l * 48 + c * 16 + k) * NPTS + p] = s;
    }
  }
}

// ---------------- spider conv via f16 MFMA; q=(t,k,c) c-fastest ----------------
template <int CPAD, int LOGC, int COUT, int OTILE>
__global__ __launch_bounds__(256) void conv_mfma_kernel(
    const char* __restrict__ ftin,        // f16 [NPTS][CPAD]
    const short* __restrict__ wb,         // f16 [OPAD][QTOT] permuted
    const float* __restrict__ b2,
    const float* __restrict__ tayg,       // f32 [48][NPTS] (this layer)
    const int* __restrict__ idx,
    float* __restrict__ pfout, int pfbstride,
    short* __restrict__ ftout, int CPADN) {
  constexpr int QTOT = CPAD * 48;
  constexpr int STEPS = QTOT / 32;
  constexpr int NJ = OTILE / 64;  // 2 (OTILE=128) or 1 (OTILE=64)
  constexpr int PW = 16 * NJ;
  __shared__ __align__(16) short As[2][OTILE * 32];
  __shared__ __align__(16) short Bs[2][64 * 32];
  __shared__ __align__(16) float tayS[48 * 64];
  __shared__ int idxS[16 * 64];
  const int t = threadIdx.x;
  const int pbase = blockIdx.x * 64;
  const int obase = blockIdx.y * OTILE;
  const int b = pbase >> 12;
  const int nbase = pbase & (NN - 1);
  const int p_loc = t >> 2;
  const int sub = t & 3;
#pragma unroll
  for (int i = 0; i < 3; ++i) {
    const int f = i * 1024 + t * 4;
    *(float4*)&tayS[f] = *(const float4*)&tayg[(size_t)(f >> 6) * NPTS + pbase + (f & 63)];
  }
  {
    const int4 mi = *(const int4*)&idx[(size_t)(pbase + p_loc) * KK + sub * 4];
    const int gb = b << 12;
    idxS[(sub * 4 + 0) * 64 + p_loc] = (gb + mi.x) << (LOGC + 1);
    idxS[(sub * 4 + 1) * 64 + p_loc] = (gb + mi.y) << (LOGC + 1);
    idxS[(sub * 4 + 2) * 64 + p_loc] = (gb + mi.z) << (LOGC + 1);
    idxS[(sub * 4 + 3) * 64 + p_loc] = (gb + mi.w) << (LOGC + 1);
  }
  const int lane = t & 63;
  const int w = t >> 6;
  const int wm = (NJ == 2) ? (w & 1) : 0;
  const int wn = (NJ == 2) ? (w >> 1) : w;
  const int fr = lane & 15;
  const int fk = lane >> 4;
  const short* aw = wb + (size_t)(obase + p_loc) * QTOT + sub * 8;
  f32x4 acc[4][NJ];
#pragma unroll
  for (int i = 0; i < 4; ++i)
#pragma unroll
    for (int j = 0; j < NJ; ++j) acc[i][j] = (f32x4)(0.0f);
  __syncthreads();  // tayS, idxS ready

  uint4 fv[2];
  float tv[2];
  auto pref = [&](int ss, int slot) {
    const int seg = ss * 32 + sub * 8;
    const int kq = seg >> LOGC;
    const int c0 = seg & (CPAD - 1);
    const int moff = idxS[(kq & 15) * 64 + p_loc];
    tv[slot] = tayS[kq * 64 + p_loc];
    fv[slot] = *(const uint4*)(ftin + moff + (c0 << 1));
  };
  auto build = [&](int slot, int dstph) {
    const __half2 t2 = __half2half2(__float2half_rn(tv[slot]));
    const uint4 f = fv[slot];
    uint4 r;
    r.x = mulh2(f.x, t2); r.y = mulh2(f.y, t2);
    r.z = mulh2(f.z, t2); r.w = mulh2(f.w, t2);
    const int chunk = sub ^ ((p_loc >> 1) & 3);
    *(uint4*)&Bs[dstph][p_loc * 32 + chunk * 8] = r;
  };
  auto dmaA = [&](int ss, int dstph) {
#pragma unroll
    for (int h = 0; h < NJ; ++h)
      __builtin_amdgcn_global_load_lds(
          (const __attribute__((address_space(1))) u32*)(aw + (size_t)h * 64 * QTOT + ss * 32),
          (__attribute__((address_space(3))) u32*)&As[dstph][h * 2048 + t * 8], 16, 0, 0);
  };
  pref(0, 0);
  dmaA(0, 0);
  pref(1, 1);
  build(0, 0);
  __syncthreads();
#pragma unroll 2
  for (int s = 0; s < STEPS; ++s) {
    const int ph = s & 1;
    if (s + 2 < STEPS) pref(s + 2, s & 1);
    if (s + 1 < STEPS) dmaA(s + 1, ph ^ 1);
    f16x8 af[4];
#pragma unroll
    for (int i = 0; i < 4; ++i)
      af[i] = *(const f16x8*)&As[ph][(wm * 64 + i * 16 + fr) * 32 + fk * 8];
    f16x8 bfr[NJ];
    const int bch = (fk ^ ((fr >> 1) & 3)) * 8;
#pragma unroll
    for (int j = 0; j < NJ; ++j)
      bfr[j] = *(const f16x8*)&Bs[ph][(wn * PW + j * 16 + fr) * 32 + bch];
    if (s + 1 < STEPS) build((s + 1) & 1, ph ^ 1);
#pragma unroll
    for (int i = 0; i < 4; ++i)
#pragma unroll
      for (int j = 0; j < NJ; ++j)
        acc[i][j] = __builtin_amdgcn_mfma_f32_16x16x32_f16(af[i], bfr[j], acc[i][j], 0, 0, 0);
    if (s + 1 < STEPS) __syncthreads();
  }
  float* outb = pfout + (size_t)b * pfbstride;
#pragma unroll
  for (int i = 0; i < 4; ++i) {
    const int o0 = obase + wm * 64 + i * 16 + fk * 4;
    if (o0 < COUT) {
      const float4 b4 = *(const float4*)&b2[o0];
#pragma unroll
      for (int j = 0; j < NJ; ++j) {
        const int p_l = wn * PW + j * 16 + fr;
        const float v0 = fmaxf(acc[i][j][0] + b4.x, 0.0f);
        const float v1 = fmaxf(acc[i][j][1] + b4.y, 0.0f);
        const float v2 = fmaxf(acc[i][j][2] + b4.z, 0.0f);
        const float v3 = fmaxf(acc[i][j][3] + b4.w, 0.0f);
        outb[(size_t)(o0 + 0) * NN + nbase + p_l] = v0;
        outb[(size_t)(o0 + 1) * NN + nbase + p_l] = v1;
        outb[(size_t)(o0 + 2) * NN + nbase + p_l] = v2;
        outb[(size_t)(o0 + 3) * NN + nbase + p_l] = v3;
        if (ftout) {
          const __half2 h01 = __floats2half2_rn(v0, v1);
          const __half2 h23 = __floats2half2_rn(v2, v3);
          uint2 pk;
          pk.x = *(const u32*)&h01;
          pk.y = *(const u32*)&h23;
          *(uint2*)&ftout[(size_t)(pbase + p_l) * CPADN + o0] = pk;
        }
      }
    }
  }
}

// ---------------- top-2 over N per (b, channel) ----------------
__global__ __launch_bounds__(256) void top2_kernel(const float* __restrict__ pf,
                                                   float* __restrict__ cat) {
  const int row = blockIdx.x;  // b*480 + ch
  const float* p = pf + (size_t)row * NN;
  float m1 = -FLT_MAX, m2 = -FLT_MAX;
  for (int i = threadIdx.x; i < NN; i += 256) {
    const float v = p[i];
    if (v > m1) { m2 = m1; m1 = v; }
    else if (v > m2) m2 = v;
  }
#pragma unroll
  for (int off = 32; off > 0; off >>= 1) {
    const float o1 = __shfl_down(m1, off, 64);
    const float o2 = __shfl_down(m2, off, 64);
    const float nm1 = fmaxf(m1, o1);
    const float nm2 = fmaxf(fminf(m1, o1), fmaxf(m2, o2));
    m1 = nm1; m2 = nm2;
  }
  __shared__ float s1[4], s2[4];
  const int wid = threadIdx.x >> 6;
  if ((threadIdx.x & 63) == 0) { s1[wid] = m1; s2[wid] = m2; }
  __syncthreads();
  if (threadIdx.x == 0) {
    m1 = s1[0]; m2 = s2[0];
#pragma unroll
    for (int w = 1; w < 4; ++w) {
      const float o1 = s1[w], o2 = s2[w];
      const float nm1 = fmaxf(m1, o1);
      const float nm2 = fmaxf(fminf(m1, o1), fmaxf(m2, o2));
      m1 = nm1; m2 = nm2;
    }
    const int b = row / 480, ch = row % 480;
    cat[b * 960 + ch * 2 + 0] = m1;
    cat[b * 960 + ch * 2 + 1] = m2;
  }
}

extern "C" void kernel_launch(void* const* d_in, const int* in_sizes, int n_in,
                              void* d_out, int out_size, void* d_ws, size_t ws_size,
                              hipStream_t stream) {
  const float* pc = (const float*)d_in[0];
  const float* w1s[4]; const float* b1s[4]; const float* w2s[4]; const float* b2s[4];
  for (int l = 0; l < 4; ++l) {
    w1s[l] = (const float*)d_in[1 + 4 * l];
    b1s[l] = (const float*)d_in[2 + 4 * l];
    w2s[l] = (const float*)d_in[3 + 4 * l];
    b2s[l] = (const float*)d_in[4 + 4 * l];
  }
  // ---- workspace layout (bytes) ----
  char* W = (char*)d_ws;
  int* idx = (int*)W;                                  // 1,048,576
  float* tayg = (float*)(W + 1048576);                 // 4 x 3,145,728 = 12,582,912
  short* wb1 = (short*)(W + 13631488);                 // 64*384    f16 =    49,152 B
  short* wb2 = wb1 + 64 * 384;                         // 64*1536       =   196,608 B
  short* wb3 = wb2 + 64 * 1536;                        // 128*3072      =   786,432 B
  short* wb4 = wb3 + 128 * 3072;                       // 256*6144      = 3,145,728 B
  short* ft0 = (short*)(W + 17809408);                 // 16384*8  f16  =   262,144 B
  short* ft1 = (short*)(W + 18071552);                 // 16384*32      = 1,048,576 B
  // knn-phase alias (consumed before tayg is written):
  float4* xyzq = (float4*)(W + 1048576);               // 262,144 B, in tayg[0]
  // conv-phase aliases:
  short* ft2 = (short*)(W + 1048576);                  // 2 MB in tayg[0]; written L2-epi (tayg[0] already consumed)
  short* ft3 = (short*)(W + 1048576 + 2097152);        // 4 MB; written L3-epi
  float* cat = (float*)d_out;                          // B*960
  float* pf = (float*)d_out + BB * 960;                // (B, 480, N)
  const int pfstride = 480 * NN;

  pc2ft_kernel<<<dim3(NPTS / 256), 256, 0, stream>>>(pc, ft0, xyzq);
  knn_select<<<dim3(NPTS), 256, 0, stream>>>(xyzq, idx);
  wcvt_kernel<<<dim3((64 * 384 / 8 + 255) / 256), 256, 0, stream>>>(w2s[0], wb1, 6, 32, 8, 3, 64 * 384 / 8);
  wcvt_kernel<<<dim3((64 * 1536 / 8 + 255) / 256), 256, 0, stream>>>(w2s[1], wb2, 32, 64, 32, 5, 64 * 1536 / 8);
  wcvt_kernel<<<dim3((128 * 3072 / 8 + 255) / 256), 256, 0, stream>>>(w2s[2], wb3, 64, 128, 64, 6, 128 * 3072 / 8);
  wcvt_kernel<<<dim3((256 * 6144 / 8 + 255) / 256), 256, 0, stream>>>(w2s[3], wb4, 128, 256, 128, 7, 256 * 6144 / 8);
  taylor_kernel<<<dim3(NPTS * KK / 256), 256, 0, stream>>>(
      pc, idx, w1s[0], b1s[0], w1s[1], b1s[1], w1s[2], b1s[2], w1s[3], b1s[3], tayg);
  conv_mfma_kernel<8, 3, 32, 64><<<dim3(NPTS / 64, 1), 256, 0, stream>>>(
      (const char*)ft0, wb1, b2s[0], tayg + 0 * (size_t)NT48, idx,
      pf + (size_t)0 * NN, pfstride, ft1, 32);
  conv_mfma_kernel<32, 5, 64, 64><<<dim3(NPTS / 64, 1), 256, 0, stream>>>(
      (const char*)ft1, wb2, b2s[1], tayg + 1 * (size_t)NT48, idx,
      pf + (size_t)32 * NN, pfstride, ft2, 64);
  conv_mfma_kernel<64, 6, 128, 64><<<dim3(NPTS / 64, 2), 256, 0, stream>>>(
      (const char*)ft2, wb3, b2s[2], tayg + 2 * (size_t)NT48, idx,
      pf + (size_t)96 * NN, pfstride, ft3, 128);
  conv_mfma_kernel<128, 7, 256, 128><<<dim3(NPTS / 64, 2), 256, 0, stream>>>(
      (const char*)ft3, wb4, b2s[3], tayg + 3 * (size_t)NT48, idx,
      pf + (size_t)224 * NN, pfstride, nullptr, 0);
  top2_kernel<<<dim3(BB * 480), 256, 0, stream>>>(pf, cat);
}

// Round 7
// 377.090 us; speedup vs baseline: 1.8741x; 1.1614x over previous
//
#include <hip/hip_runtime.h>
#include <hip/hip_fp16.h>
#include <cfloat>

#define BB 4
#define NN 4096
#define KK 16
#define NPTS (BB * NN)      // 16384
#define NT48 (48 * NPTS)    // per-layer tay floats, layout [48][NPTS]

typedef __attribute__((ext_vector_type(8))) _Float16 f16x8;
typedef __attribute__((ext_vector_type(4))) float f32x4;
typedef unsigned int u32;
typedef unsigned long long u64;

__device__ __forceinline__ short f2h(float v) {
  __half h = __float2half_rn(v);
  return __half_as_short(h);
}
__device__ __forceinline__ u32 mulh2(u32 a, __half2 t) {
  __half2 x = __hmul2(*(__half2*)&a, t);
  return *(u32*)&x;
}

// ---------------- pc -> ft0 f16 [p][8] + xyzq f32 [p][4] ----------------
__global__ __launch_bounds__(256) void pc2ft_kernel(const float* __restrict__ pc,
                                                    short* __restrict__ ft0,
                                                    float4* __restrict__ xyzq) {
  const int i = blockIdx.x * 256 + threadIdx.x;
  if (i >= NPTS) return;
  const float* s = pc + (size_t)i * 6;
  short* d = ft0 + (size_t)i * 8;
#pragma unroll
  for (int c = 0; c < 6; ++c) d[c] = f2h(s[c]);
  d[6] = 0; d[7] = 0;
  const float x = s[0], y = s[1], z = s[2];
  xyzq[i] = make_float4(x, y, z, fmaf(z, z, fmaf(y, y, x * x)));
}

// ---------------- KNN: min-threshold select, one block per query ----------------
// Exact top-16 by (d2, idx) lexicographic (== jax top_k tie semantics).
// T = min over waves of (16th-smallest of the wave's 64 thread-mins).
// Sound: <=15 thread-mins can be strictly below d2_16, so sorted[15] >= d2_16.
// Threshold via one 21-step bitonic sort; extraction via rank counting.
__global__ __launch_bounds__(256) void knn_select(const float4* __restrict__ xyzq,
                                                  int* __restrict__ idx_out) {
  __shared__ float wT[4];
  __shared__ u64 list[128];
  __shared__ int lcnt;
  const int g = blockIdx.x;   // query point (b*4096 + n)
  const int b = g >> 12;
  const int t = threadIdx.x;
  const int lane = t & 63;
  const float4* base = xyzq + (b << 12);
  const float4 q = xyzq[g];
  float d2v[16];
  float mymin = FLT_MAX;
#pragma unroll
  for (int i = 0; i < 16; ++i) {
    const float4 c = base[i * 256 + t];
    const float dot = fmaf(q.z, c.z, fmaf(q.y, c.y, q.x * c.x));
    d2v[i] = fmaf(-2.0f, dot, q.w + c.w);
    mymin = fminf(mymin, d2v[i]);
  }
  if (t == 0) lcnt = 0;
  // ---- in-wave bitonic sort (ascending) of 64 thread-mins ----
  float v = mymin;
#pragma unroll
  for (int k = 2; k <= 64; k <<= 1) {
#pragma unroll
    for (int j = k >> 1; j >= 1; j >>= 1) {
      const float o = __shfl_xor(v, j, 64);
      const bool take_min = (((lane & k) == 0) == ((lane & j) == 0));
      v = take_min ? fminf(v, o) : fmaxf(v, o);
    }
  }
  const float tw = __shfl(v, 15, 64);  // 16th smallest in this wave
  if (lane == 0) wT[t >> 6] = tw;
  __syncthreads();  // covers wT + lcnt
  const float T = fminf(fminf(wT[0], wT[1]), fminf(wT[2], wT[3]));
  // ---- collect all candidates with d2 <= T (superset of top-16) ----
#pragma unroll
  for (int i = 0; i < 16; ++i) {
    if (d2v[i] <= T) {
      const u32 bits = __float_as_uint(d2v[i]);
      const u32 key = bits ^ ((u32)((int)bits >> 31) | 0x80000000u);
      const int pos = atomicAdd(&lcnt, 1);
      if (pos < 128) list[pos] = ((u64)key << 32) | (u32)(i * 256 + t);
    }
  }
  __syncthreads();
  // ---- rank-based extraction: lanes 0..127 own one entry each ----
  if (t < 128) {
    const int m = min(lcnt, 128);  // typical m ~ 17-30; 128 = tie-safety cap
    const u64 my = (t < m) ? list[t] : ~0ull;
    int rank = 0;
#pragma unroll 4
    for (int i = 0; i < m; ++i) rank += (list[i] < my) ? 1 : 0;
    if (t < m && rank < 16)
      idx_out[(size_t)g * KK + rank] = (int)(my & 0xFFFFFFFFull);
  }
}

// ---------------- weights fp32 (o,(c,t),k) -> f16 permuted [o][(t,k,c)] padded ----------------
__global__ __launch_bounds__(256) void wcvt_kernel(const float* __restrict__ w2,
                                                   short* __restrict__ wb,
                                                   int CIN, int COUT, int CPAD, int LOGC,
                                                   int total8) {
  const int i = blockIdx.x * 256 + threadIdx.x;
  if (i >= total8) return;
  const int q8 = i * 8;
  const int QT = CPAD * 48;
  const int o = q8 / QT;
  const int r = q8 - o * QT;
  const int kq = r >> LOGC;
  const int c0 = r & (CPAD - 1);
  const int tt = kq >> 4;
  const int k = kq & 15;
  short h[8];
#pragma unroll
  for (int j = 0; j < 8; ++j) {
    const int c = c0 + j;
    const float v = (o < COUT && c < CIN) ? w2[(size_t)o * CIN * 48 + (c * 3 + tt) * 16 + k] : 0.0f;
    h[j] = f2h(v);
  }
  short* d = wb + (size_t)o * QT + r;
#pragma unroll
  for (int j = 0; j < 8; ++j) d[j] = h[j];
}

// ---------------- tay_g[l][t*16+k][p] = (w1_l @ taylor(rel) + b1_l) ----------------
__global__ __launch_bounds__(256) void taylor_kernel(
    const float* __restrict__ pc, const int* __restrict__ idx,
    const float* __restrict__ w1_1, const float* __restrict__ b1_1,
    const float* __restrict__ w1_2, const float* __restrict__ b1_2,
    const float* __restrict__ w1_3, const float* __restrict__ b1_3,
    const float* __restrict__ w1_4, const float* __restrict__ b1_4,
    float* __restrict__ tayg) {
  const int i = blockIdx.x * 256 + threadIdx.x;  // p fastest, then k
  if (i >= NPTS * KK) return;
  const int p = i & (NPTS - 1);
  const int k = i >> 14;
  const int n = p & (NN - 1);
  const int b = p >> 12;
  const float* pcb = pc + (size_t)b * NN * 6;
  const int m = idx[(size_t)p * KK + k];
  const float x = pcb[m * 6 + 0] - pcb[n * 6 + 0];
  const float y = pcb[m * 6 + 1] - pcb[n * 6 + 1];
  const float z = pcb[m * 6 + 2] - pcb[n * 6 + 2];
  float tb[20];
  tb[0] = 1.0f; tb[1] = x; tb[2] = y; tb[3] = z;
  tb[4] = x * x; tb[5] = x * y; tb[6] = x * z;
  tb[7] = y * y; tb[8] = y * z; tb[9] = z * z;
  tb[10] = tb[4] * x; tb[11] = tb[4] * y; tb[12] = tb[4] * z;
  tb[13] = tb[5] * y; tb[14] = tb[5] * z; tb[15] = tb[6] * z;
  tb[16] = tb[7] * y; tb[17] = tb[7] * z; tb[18] = tb[8] * z; tb[19] = tb[9] * z;
  const float* w1s[4] = {w1_1, w1_2, w1_3, w1_4};
  const float* b1s[4] = {b1_1, b1_2, b1_3, b1_4};
#pragma unroll
  for (int l = 0; l < 4; ++l) {
    const float* w1 = w1s[l];
    const float* b1 = b1s[l];
#pragma unroll
    for (int c = 0; c < 3; ++c) {
      float s = b1[c];
#pragma unroll
      for (int j = 0; j < 20; ++j) s = fmaf(w1[c * 20 + j], tb[j], s);
      tayg[(size_t)(l * 48 + c * 16 + k) * NPTS + p] = s;
    }
  }
}

// ---------------- spider conv via f16 MFMA; q=(t,k,c) c-fastest ----------------
template <int CPAD, int LOGC, int COUT, int OTILE>
__global__ __launch_bounds__(256) void conv_mfma_kernel(
    const char* __restrict__ ftin,        // f16 [NPTS][CPAD]
    const short* __restrict__ wb,         // f16 [OPAD][QTOT] permuted
    const float* __restrict__ b2,
    const float* __restrict__ tayg,       // f32 [48][NPTS] (this layer)
    const int* __restrict__ idx,
    float* __restrict__ pfout, int pfbstride,
    short* __restrict__ ftout, int CPADN) {
  constexpr int QTOT = CPAD * 48;
  constexpr int STEPS = QTOT / 32;
  constexpr int NJ = OTILE / 64;  // 2 (OTILE=128) or 1 (OTILE=64)
  constexpr int PW = 16 * NJ;
  __shared__ __align__(16) short As[2][OTILE * 32];
  __shared__ __align__(16) short Bs[2][64 * 32];
  __shared__ __align__(16) float tayS[48 * 64];
  __shared__ int idxS[16 * 64];
  const int t = threadIdx.x;
  const int pbase = blockIdx.x * 64;
  const int obase = blockIdx.y * OTILE;
  const int b = pbase >> 12;
  const int nbase = pbase & (NN - 1);
  const int p_loc = t >> 2;
  const int sub = t & 3;
#pragma unroll
  for (int i = 0; i < 3; ++i) {
    const int f = i * 1024 + t * 4;
    *(float4*)&tayS[f] = *(const float4*)&tayg[(size_t)(f >> 6) * NPTS + pbase + (f & 63)];
  }
  {
    const int4 mi = *(const int4*)&idx[(size_t)(pbase + p_loc) * KK + sub * 4];
    const int gb = b << 12;
    idxS[(sub * 4 + 0) * 64 + p_loc] = (gb + mi.x) << (LOGC + 1);
    idxS[(sub * 4 + 1) * 64 + p_loc] = (gb + mi.y) << (LOGC + 1);
    idxS[(sub * 4 + 2) * 64 + p_loc] = (gb + mi.z) << (LOGC + 1);
    idxS[(sub * 4 + 3) * 64 + p_loc] = (gb + mi.w) << (LOGC + 1);
  }
  const int lane = t & 63;
  const int w = t >> 6;
  const int wm = (NJ == 2) ? (w & 1) : 0;
  const int wn = (NJ == 2) ? (w >> 1) : w;
  const int fr = lane & 15;
  const int fk = lane >> 4;
  const short* aw = wb + (size_t)(obase + p_loc) * QTOT + sub * 8;
  f32x4 acc[4][NJ];
#pragma unroll
  for (int i = 0; i < 4; ++i)
#pragma unroll
    for (int j = 0; j < NJ; ++j) acc[i][j] = (f32x4)(0.0f);
  __syncthreads();  // tayS, idxS ready

  uint4 fv[2];
  float tv[2];
  auto pref = [&](int ss, int slot) {
    const int seg = ss * 32 + sub * 8;
    const int kq = seg >> LOGC;
    const int c0 = seg & (CPAD - 1);
    const int moff = idxS[(kq & 15) * 64 + p_loc];
    tv[slot] = tayS[kq * 64 + p_loc];
    fv[slot] = *(const uint4*)(ftin + moff + (c0 << 1));
  };
  auto build = [&](int slot, int dstph) {
    const __half2 t2 = __half2half2(__float2half_rn(tv[slot]));
    const uint4 f = fv[slot];
    uint4 r;
    r.x = mulh2(f.x, t2); r.y = mulh2(f.y, t2);
    r.z = mulh2(f.z, t2); r.w = mulh2(f.w, t2);
    const int chunk = sub ^ ((p_loc >> 1) & 3);
    *(uint4*)&Bs[dstph][p_loc * 32 + chunk * 8] = r;
  };
  auto dmaA = [&](int ss, int dstph) {
#pragma unroll
    for (int h = 0; h < NJ; ++h)
      __builtin_amdgcn_global_load_lds(
          (const __attribute__((address_space(1))) u32*)(aw + (size_t)h * 64 * QTOT + ss * 32),
          (__attribute__((address_space(3))) u32*)&As[dstph][h * 2048 + t * 8], 16, 0, 0);
  };
  pref(0, 0);
  dmaA(0, 0);
  pref(1, 1);
  build(0, 0);
  __syncthreads();
#pragma unroll 2
  for (int s = 0; s < STEPS; ++s) {
    const int ph = s & 1;
    if (s + 2 < STEPS) pref(s + 2, s & 1);
    if (s + 1 < STEPS) dmaA(s + 1, ph ^ 1);
    f16x8 af[4];
#pragma unroll
    for (int i = 0; i < 4; ++i)
      af[i] = *(const f16x8*)&As[ph][(wm * 64 + i * 16 + fr) * 32 + fk * 8];
    f16x8 bfr[NJ];
    const int bch = (fk ^ ((fr >> 1) & 3)) * 8;
#pragma unroll
    for (int j = 0; j < NJ; ++j)
      bfr[j] = *(const f16x8*)&Bs[ph][(wn * PW + j * 16 + fr) * 32 + bch];
    if (s + 1 < STEPS) build((s + 1) & 1, ph ^ 1);
#pragma unroll
    for (int i = 0; i < 4; ++i)
#pragma unroll
      for (int j = 0; j < NJ; ++j)
        acc[i][j] = __builtin_amdgcn_mfma_f32_16x16x32_f16(af[i], bfr[j], acc[i][j], 0, 0, 0);
    if (s + 1 < STEPS) __syncthreads();
  }
  float* outb = pfout + (size_t)b * pfbstride;
#pragma unroll
  for (int i = 0; i < 4; ++i) {
    const int o0 = obase + wm * 64 + i * 16 + fk * 4;
    if (o0 < COUT) {
      const float4 b4 = *(const float4*)&b2[o0];
#pragma unroll
      for (int j = 0; j < NJ; ++j) {
        const int p_l = wn * PW + j * 16 + fr;
        const float v0 = fmaxf(acc[i][j][0] + b4.x, 0.0f);
        const float v1 = fmaxf(acc[i][j][1] + b4.y, 0.0f);
        const float v2 = fmaxf(acc[i][j][2] + b4.z, 0.0f);
        const float v3 = fmaxf(acc[i][j][3] + b4.w, 0.0f);
        outb[(size_t)(o0 + 0) * NN + nbase + p_l] = v0;
        outb[(size_t)(o0 + 1) * NN + nbase + p_l] = v1;
        outb[(size_t)(o0 + 2) * NN + nbase + p_l] = v2;
        outb[(size_t)(o0 + 3) * NN + nbase + p_l] = v3;
        if (ftout) {
          const __half2 h01 = __floats2half2_rn(v0, v1);
          const __half2 h23 = __floats2half2_rn(v2, v3);
          uint2 pk;
          pk.x = *(const u32*)&h01;
          pk.y = *(const u32*)&h23;
          *(uint2*)&ftout[(size_t)(pbase + p_l) * CPADN + o0] = pk;
        }
      }
    }
  }
}

// ---------------- top-2 over N per (b, channel) ----------------
__global__ __launch_bounds__(256) void top2_kernel(const float* __restrict__ pf,
                                                   float* __restrict__ cat) {
  const int row = blockIdx.x;  // b*480 + ch
  const float* p = pf + (size_t)row * NN;
  float m1 = -FLT_MAX, m2 = -FLT_MAX;
  for (int i = threadIdx.x; i < NN; i += 256) {
    const float v = p[i];
    if (v > m1) { m2 = m1; m1 = v; }
    else if (v > m2) m2 = v;
  }
#pragma unroll
  for (int off = 32; off > 0; off >>= 1) {
    const float o1 = __shfl_down(m1, off, 64);
    const float o2 = __shfl_down(m2, off, 64);
    const float nm1 = fmaxf(m1, o1);
    const float nm2 = fmaxf(fminf(m1, o1), fmaxf(m2, o2));
    m1 = nm1; m2 = nm2;
  }
  __shared__ float s1[4], s2[4];
  const int wid = threadIdx.x >> 6;
  if ((threadIdx.x & 63) == 0) { s1[wid] = m1; s2[wid] = m2; }
  __syncthreads();
  if (threadIdx.x == 0) {
    m1 = s1[0]; m2 = s2[0];
#pragma unroll
    for (int w = 1; w < 4; ++w) {
      const float o1 = s1[w], o2 = s2[w];
      const float nm1 = fmaxf(m1, o1);
      const float nm2 = fmaxf(fminf(m1, o1), fmaxf(m2, o2));
      m1 = nm1; m2 = nm2;
    }
    const int b = row / 480, ch = row % 480;
    cat[b * 960 + ch * 2 + 0] = m1;
    cat[b * 960 + ch * 2 + 1] = m2;
  }
}

extern "C" void kernel_launch(void* const* d_in, const int* in_sizes, int n_in,
                              void* d_out, int out_size, void* d_ws, size_t ws_size,
                              hipStream_t stream) {
  const float* pc = (const float*)d_in[0];
  const float* w1s[4]; const float* b1s[4]; const float* w2s[4]; const float* b2s[4];
  for (int l = 0; l < 4; ++l) {
    w1s[l] = (const float*)d_in[1 + 4 * l];
    b1s[l] = (const float*)d_in[2 + 4 * l];
    w2s[l] = (const float*)d_in[3 + 4 * l];
    b2s[l] = (const float*)d_in[4 + 4 * l];
  }
  // ---- workspace layout (bytes) ----
  char* W = (char*)d_ws;
  int* idx = (int*)W;                                  // 1,048,576
  float* tayg = (float*)(W + 1048576);                 // 4 x 3,145,728 = 12,582,912
  short* wb1 = (short*)(W + 13631488);                 // 64*384    f16 =    49,152 B
  short* wb2 = wb1 + 64 * 384;                         // 64*1536       =   196,608 B
  short* wb3 = wb2 + 64 * 1536;                        // 128*3072      =   786,432 B
  short* wb4 = wb3 + 128 * 3072;                       // 256*6144      = 3,145,728 B
  short* ft0 = (short*)(W + 17809408);                 // 16384*8  f16  =   262,144 B
  short* ft1 = (short*)(W + 18071552);                 // 16384*32      = 1,048,576 B
  // knn-phase alias (consumed before tayg is written):
  float4* xyzq = (float4*)(W + 1048576);               // 262,144 B, in tayg[0]
  // conv-phase aliases:
  short* ft2 = (short*)(W + 1048576);                  // 2 MB in tayg[0]; written L2-epi (tayg[0] already consumed)
  short* ft3 = (short*)(W + 1048576 + 2097152);        // 4 MB; written L3-epi
  float* cat = (float*)d_out;                          // B*960
  float* pf = (float*)d_out + BB * 960;                // (B, 480, N)
  const int pfstride = 480 * NN;

  pc2ft_kernel<<<dim3(NPTS / 256), 256, 0, stream>>>(pc, ft0, xyzq);
  knn_select<<<dim3(NPTS), 256, 0, stream>>>(xyzq, idx);
  wcvt_kernel<<<dim3((64 * 384 / 8 + 255) / 256), 256, 0, stream>>>(w2s[0], wb1, 6, 32, 8, 3, 64 * 384 / 8);
  wcvt_kernel<<<dim3((64 * 1536 / 8 + 255) / 256), 256, 0, stream>>>(w2s[1], wb2, 32, 64, 32, 5, 64 * 1536 / 8);
  wcvt_kernel<<<dim3((128 * 3072 / 8 + 255) / 256), 256, 0, stream>>>(w2s[2], wb3, 64, 128, 64, 6, 128 * 3072 / 8);
  wcvt_kernel<<<dim3((256 * 6144 / 8 + 255) / 256), 256, 0, stream>>>(w2s[3], wb4, 128, 256, 128, 7, 256 * 6144 / 8);
  taylor_kernel<<<dim3(NPTS * KK / 256), 256, 0, stream>>>(
      pc, idx, w1s[0], b1s[0], w1s[1], b1s[1], w1s[2], b1s[2], w1s[3], b1s[3], tayg);
  conv_mfma_kernel<8, 3, 32, 64><<<dim3(NPTS / 64, 1), 256, 0, stream>>>(
      (const char*)ft0, wb1, b2s[0], tayg + 0 * (size_t)NT48, idx,
      pf + (size_t)0 * NN, pfstride, ft1, 32);
  conv_mfma_kernel<32, 5, 64, 64><<<dim3(NPTS / 64, 1), 256, 0, stream>>>(
      (const char*)ft1, wb2, b2s[1], tayg + 1 * (size_t)NT48, idx,
      pf + (size_t)32 * NN, pfstride, ft2, 64);
  conv_mfma_kernel<64, 6, 128, 64><<<dim3(NPTS / 64, 2), 256, 0, stream>>>(
      (const char*)ft2, wb3, b2s[2], tayg + 2 * (size_t)NT48, idx,
      pf + (size_t)96 * NN, pfstride, ft3, 128);
  conv_mfma_kernel<128, 7, 256, 128><<<dim3(NPTS / 64, 2), 256, 0, stream>>>(
      (const char*)ft3, wb4, b2s[3], tayg + 3 * (size_t)NT48, idx,
      pf + (size_t)224 * NN, pfstride, nullptr, 0);
  top2_kernel<<<dim3(BB * 480), 256, 0, stream>>>(pf, cat);
}